// Round 1
// baseline (1709.529 us; speedup 1.0000x reference)
//
#include <hip/hip_runtime.h>
#include <math.h>

// ---------------------------------------------------------------------------
// Aux-free MoE, capacity-routed top-2, E=16 experts.
// B=16384, F=1024, H=4096, O=1024, cap=2560 (multiple of 256 -> capR==cap).
// Heavy GEMMs: 256x256-tile 8-phase bf16 MFMA (m201-style: counted vmcnt,
// raw s_barrier, XOR-swizzled LDS, setprio around MFMA clusters).
// Gating in fp64 to match the reference's expert selection exactly.
// ---------------------------------------------------------------------------

typedef __attribute__((ext_vector_type(8))) short bf16x8;
typedef __attribute__((ext_vector_type(4))) float floatx4;

static __device__ __forceinline__ unsigned short f2bf(float f) {
  union { float f; unsigned u; } v; v.f = f;
  unsigned u = v.u;
  return (unsigned short)((u + 0x7fffu + ((u >> 16) & 1u)) >> 16);  // RNE
}

static __device__ __forceinline__ void gload_lds16(const void* g, void* l) {
  __builtin_amdgcn_global_load_lds(
      (const __attribute__((address_space(1))) unsigned int*)g,
      (__attribute__((address_space(3))) unsigned int*)l, 16, 0, 0);
}

// --------------------------- fp32 -> bf16 convert ---------------------------
__global__ void k_cvt_bf16(const float* __restrict__ src,
                           unsigned short* __restrict__ dst, long n4) {
  long i = (long)blockIdx.x * blockDim.x + threadIdx.x;
  if (i >= n4) return;
  float4 f = ((const float4*)src)[i];
  ushort4 o;
  o.x = f2bf(f.x); o.y = f2bf(f.y); o.z = f2bf(f.z); o.w = f2bf(f.w);
  ((ushort4*)dst)[i] = o;
}

// ----------------- transpose + convert: (E,K,N) f32 -> (E,N,K) bf16 --------
__global__ void k_txp_bf16(const float* __restrict__ src,
                           unsigned short* __restrict__ dst, int Kd, int Nd) {
  __shared__ float tile[32][33];
  int e = blockIdx.z;
  int n0 = blockIdx.x * 32;
  int k0 = blockIdx.y * 32;
  int tx = threadIdx.x;  // 0..31
  int ty = threadIdx.y;  // 0..7
  const float* s = src + (size_t)e * Kd * Nd;
#pragma unroll
  for (int j = 0; j < 4; ++j) {
    int k = ty + j * 8;
    tile[k][tx] = s[(size_t)(k0 + k) * Nd + n0 + tx];
  }
  __syncthreads();
  unsigned short* d = dst + (size_t)e * Kd * Nd;
#pragma unroll
  for (int j = 0; j < 4; ++j) {
    int n = ty + j * 8;
    d[(size_t)(n0 + n) * Kd + k0 + tx] = f2bf(tile[tx][n]);
  }
}

// ------------------------------- gating (fp64) ------------------------------
__global__ __launch_bounds__(256) void k_gating(
    const float* __restrict__ feat, const float* __restrict__ Wg,
    const float* __restrict__ bg, const float* __restrict__ ebias,
    int* __restrict__ topki, float* __restrict__ topkw,
    int* __restrict__ hist, int B, int F) {
  __shared__ float WgS[16 * 1024];  // 64 KB
  for (int i = threadIdx.x; i < 16 * F; i += blockDim.x) WgS[i] = Wg[i];
  __syncthreads();
  int lane = threadIdx.x & 63;
  int wid = threadIdx.x >> 6;
  int gw = blockIdx.x * 4 + wid;
  int nw = gridDim.x * 4;
  int per = B / nw;
  for (int it = 0; it < per; ++it) {
    int t = gw * per + it;
    double acc[16];
#pragma unroll
    for (int e = 0; e < 16; ++e) acc[e] = 0.0;
    const float* fr = feat + (size_t)t * F;
    for (int c = 0; c < F / 64; ++c) {
      double fd = (double)fr[c * 64 + lane];
#pragma unroll
      for (int e = 0; e < 16; ++e)
        acc[e] += fd * (double)WgS[e * F + c * 64 + lane];
    }
#pragma unroll
    for (int e = 0; e < 16; ++e) {
#pragma unroll
      for (int off = 32; off >= 1; off >>= 1)
        acc[e] += __shfl_xor(acc[e], off);
    }
    double s[16];
#pragma unroll
    for (int e = 0; e < 16; ++e)
      s[e] = acc[e] + (double)bg[e] + (double)ebias[e];
    int e1 = 0; double s1 = s[0];
#pragma unroll
    for (int e = 1; e < 16; ++e) if (s[e] > s1) { s1 = s[e]; e1 = e; }
    int e2 = -1; double s2 = -1e300;
#pragma unroll
    for (int e = 0; e < 16; ++e)
      if (e != e1 && s[e] > s2) { s2 = s[e]; e2 = e; }
    double d = exp(s2 - s1);
    float w1 = (float)(1.0 / (1.0 + d));
    float w2 = (float)(d / (1.0 + d));
    if (lane == 0) {
      topki[t * 2 + 0] = e1; topki[t * 2 + 1] = e2;
      topkw[t * 2 + 0] = w1; topkw[t * 2 + 1] = w2;
      atomicAdd(&hist[(t >> 8) * 16 + e1], 1);
      atomicAdd(&hist[(t >> 8) * 16 + e2], 1);
    }
  }
}

// ------------------------- chunk-offset scan (1 block) ----------------------
__global__ void k_scan(const int* __restrict__ hist, int* __restrict__ choff,
                       int* __restrict__ cntcl, int nchunk, int cap) {
  int e = threadIdx.x;
  if (e < 16) {
    int off = 0;
    for (int c = 0; c < nchunk; ++c) {
      choff[c * 16 + e] = off;
      off += hist[c * 16 + e];
    }
    cntcl[e] = off < cap ? off : cap;
  }
}

// -------------------- build per-expert slot lists (ordered) -----------------
__global__ __launch_bounds__(64) void k_build(
    const int* __restrict__ topki, const float* __restrict__ topkw,
    const int* __restrict__ choff, int* __restrict__ list,
    float* __restrict__ wlist, int cap, int capR) {
  int c = blockIdx.x;
  int lane = threadIdx.x;
  int run[16];
#pragma unroll
  for (int e = 0; e < 16; ++e) run[e] = choff[c * 16 + e];
  unsigned long long below = (lane == 63) ? 0x7fffffffffffffffull
                                          : ((1ull << lane) - 1ull);
  for (int r = 0; r < 4; ++r) {
    int t = c * 256 + r * 64 + lane;
    int e1 = topki[t * 2 + 0], e2 = topki[t * 2 + 1];
    float w1 = topkw[t * 2 + 0], w2 = topkw[t * 2 + 1];
    int p1 = -1, p2 = -1;
#pragma unroll
    for (int e = 0; e < 16; ++e) {
      unsigned long long m = __ballot(e1 == e) | __ballot(e2 == e);
      int rk = run[e] + __popcll(m & below);
      if (e1 == e) p1 = rk;
      if (e2 == e) p2 = rk;
      run[e] += __popcll(m);
    }
    if (p1 >= 0 && p1 < cap) { list[e1 * capR + p1] = t; wlist[e1 * capR + p1] = w1; }
    if (p2 >= 0 && p2 < cap) { list[e2 * capR + p2] = t; wlist[e2 * capR + p2] = w2; }
  }
}

// ----------------------- pad unused slots (token 0, w 0) --------------------
__global__ void k_padfill(const int* __restrict__ cntcl, int* __restrict__ list,
                          float* __restrict__ wlist, int capR) {
  int e = blockIdx.x;
  int cnt = cntcl[e];
  for (int s = cnt + (int)threadIdx.x; s < capR; s += (int)blockDim.x) {
    list[e * capR + s] = 0;
    wlist[e * capR + s] = 0.0f;
  }
}

// ------------------------------ bf16 MFMA GEMM ------------------------------
// 256x256 tile, BK=64, 8 waves (2Mx4N), 8-phase schedule w/ counted vmcnt.
// LDS: 2 buffers x 64 KB; buffer = A_k0(16K) | B_k0(16K) | A_k1(16K) | B_k1(16K).
// Each half-tile: 256 rows x 32 bf16 (64 B/row), XOR-swizzled 16B chunks:
//   chunk_pos = chunk ^ ((row>>1)&3), applied on the pre-swizzled global
//   source address (linear global_load_lds dest) and again on the ds_read.
// MODE 0: A rows gathered from featbf via list; epilogue relu(acc+b1) -> Hout
// MODE 1: A rows from Hbuf; epilogue w*(acc+b2) atomic-scatter -> out[token]
#define VM_WAIT4 asm volatile("s_waitcnt vmcnt(4)" ::: "memory")
#define VM_WAIT0 asm volatile("s_waitcnt vmcnt(0)" ::: "memory")

template <int MODE>
__global__ __launch_bounds__(512, 2) void k_gemm(
    const unsigned short* __restrict__ A, const unsigned short* __restrict__ Bt,
    const float* __restrict__ bias, const int* __restrict__ list,
    const float* __restrict__ wlist, const int* __restrict__ cntcl,
    unsigned short* __restrict__ Hout, float* __restrict__ out,
    int Kd, int Nd, int RT, int NT, int capR) {
  __shared__ __align__(16) char smem[131072];
  int bid = blockIdx.x;
  int e = bid / (RT * NT);
  int rt = (bid / NT) % RT;
  int nt = bid % NT;
  int cnt = cntcl[e];
  int r0 = rt * 256;
  if (r0 >= cnt) return;  // block-uniform early exit
  int n0 = nt * 256;

  int tid = threadIdx.x;
  int lane = tid & 63;
  int wid = tid >> 6;      // 0..7
  int wr = wid >> 2;       // 0..1  (M half)
  int wc = wid & 3;        // 0..3  (N quarter)
  int l16 = lane & 15, q = lane >> 4;

  // ---- staging source pointers (2 rounds per half-tile) ----
  const char* gA[2];
  const char* gB[2];
  int scg = lane & 3;           // 16B chunk within 64B k-half
  int srl = lane >> 2;          // row-within-16 group
#pragma unroll
  for (int p = 0; p < 2; ++p) {
    int r = (p * 8 + wid) * 16 + srl;             // 0..255 (tile-local row)
    int cgs = scg ^ ((r >> 1) & 3);               // pre-swizzled source chunk
    const unsigned short* arow;
    if (MODE == 0) {
      int tok = list[e * capR + r0 + r];
      arow = A + (size_t)tok * Kd;
    } else {
      arow = A + (size_t)(e * capR + r0 + r) * Kd;
    }
    gA[p] = (const char*)arow + cgs * 16;
    const unsigned short* brow =
        Bt + (size_t)e * Nd * Kd + (size_t)(n0 + r) * Kd;
    gB[p] = (const char*)brow + cgs * 16;
  }
  int stofs[2];
#pragma unroll
  for (int p = 0; p < 2; ++p) stofs[p] = (p * 8 + wid) * 1024;  // wave-uniform

  floatx4 acc[8][4];
#pragma unroll
  for (int i = 0; i < 8; ++i)
#pragma unroll
    for (int j = 0; j < 4; ++j) acc[i][j] = 0.0f;

  // ---- read-side swizzle (row bits 1..2 == lane bits 1..2) ----
  int sw = ((q ^ ((lane >> 1) & 3)) << 4);
  int arl = wr * 128 + l16;  // A row base within 256-row tile
  int brl = wc * 64 + l16;   // B row base within 256-row tile

  int nk = Kd / 64;

  // ---- prologue: stage all 4 half-tiles of K-tile 0 into buffer 0 ----
#pragma unroll
  for (int p = 0; p < 2; ++p) gload_lds16(gA[p], smem + stofs[p]);
#pragma unroll
  for (int p = 0; p < 2; ++p) gload_lds16(gB[p], smem + 16384 + stofs[p]);
#pragma unroll
  for (int p = 0; p < 2; ++p) gload_lds16(gA[p] + 64, smem + 32768 + stofs[p]);
#pragma unroll
  for (int p = 0; p < 2; ++p) gload_lds16(gB[p] + 64, smem + 49152 + stofs[p]);
  VM_WAIT4;  // A_k0,B_k0 of tile 0 complete in this wave
  __builtin_amdgcn_s_barrier();  // ...and in all waves

  bf16x8 af[8], bf[4];

  for (int t = 0; t < nk; ++t) {
    const char* Cb = smem + (t & 1) * 65536;
    char* Nb = smem + (((t & 1) ^ 1) * 65536);
    int gk = (t + 1) * 128;        // byte offset of next K-tile in a row
    bool pre = (t + 1) < nk;

    // ---------------- phase 1: kk0, j=0,1 ----------------
#pragma unroll
    for (int i = 0; i < 8; ++i)
      af[i] = *(const bf16x8*)(Cb + (arl + i * 16) * 64 + sw);
#pragma unroll
    for (int j = 0; j < 2; ++j)
      bf[j] = *(const bf16x8*)(Cb + 16384 + (brl + j * 16) * 64 + sw);
    if (pre) {
#pragma unroll
      for (int p = 0; p < 2; ++p) gload_lds16(gA[p] + gk, Nb + stofs[p]);
    }
    __builtin_amdgcn_s_barrier();
    __builtin_amdgcn_s_setprio(1);
#pragma unroll
    for (int j = 0; j < 2; ++j)
#pragma unroll
      for (int i = 0; i < 8; ++i)
        acc[i][j] = __builtin_amdgcn_mfma_f32_16x16x32_bf16(af[i], bf[j],
                                                            acc[i][j], 0, 0, 0);
    __builtin_amdgcn_s_setprio(0);
    __builtin_amdgcn_s_barrier();

    // ---------------- phase 2: kk0, j=2,3 ----------------
#pragma unroll
    for (int j = 2; j < 4; ++j)
      bf[j] = *(const bf16x8*)(Cb + 16384 + (brl + j * 16) * 64 + sw);
    if (pre) {
#pragma unroll
      for (int p = 0; p < 2; ++p)
        gload_lds16(gB[p] + gk, Nb + 16384 + stofs[p]);
    }
    __builtin_amdgcn_s_barrier();
    __builtin_amdgcn_s_setprio(1);
#pragma unroll
    for (int j = 2; j < 4; ++j)
#pragma unroll
      for (int i = 0; i < 8; ++i)
        acc[i][j] = __builtin_amdgcn_mfma_f32_16x16x32_bf16(af[i], bf[j],
                                                            acc[i][j], 0, 0, 0);
    __builtin_amdgcn_s_setprio(0);
    if (pre) { VM_WAIT4; } else { VM_WAIT0; }  // publish A_k1,B_k1 of tile t
    __builtin_amdgcn_s_barrier();

    // ---------------- phase 3: kk1, j=0,1 ----------------
#pragma unroll
    for (int i = 0; i < 8; ++i)
      af[i] = *(const bf16x8*)(Cb + 32768 + (arl + i * 16) * 64 + sw);
#pragma unroll
    for (int j = 0; j < 2; ++j)
      bf[j] = *(const bf16x8*)(Cb + 49152 + (brl + j * 16) * 64 + sw);
    if (pre) {
#pragma unroll
      for (int p = 0; p < 2; ++p)
        gload_lds16(gA[p] + gk + 64, Nb + 32768 + stofs[p]);
    }
    __builtin_amdgcn_s_barrier();
    __builtin_amdgcn_s_setprio(1);
#pragma unroll
    for (int j = 0; j < 2; ++j)
#pragma unroll
      for (int i = 0; i < 8; ++i)
        acc[i][j] = __builtin_amdgcn_mfma_f32_16x16x32_bf16(af[i], bf[j],
                                                            acc[i][j], 0, 0, 0);
    __builtin_amdgcn_s_setprio(0);
    __builtin_amdgcn_s_barrier();

    // ---------------- phase 4: kk1, j=2,3 ----------------
#pragma unroll
    for (int j = 2; j < 4; ++j)
      bf[j] = *(const bf16x8*)(Cb + 49152 + (brl + j * 16) * 64 + sw);
    if (pre) {
#pragma unroll
      for (int p = 0; p < 2; ++p)
        gload_lds16(gB[p] + gk + 64, Nb + 49152 + stofs[p]);
    }
    __builtin_amdgcn_s_barrier();
    __builtin_amdgcn_s_setprio(1);
#pragma unroll
    for (int j = 2; j < 4; ++j)
#pragma unroll
      for (int i = 0; i < 8; ++i)
        acc[i][j] = __builtin_amdgcn_mfma_f32_16x16x32_bf16(af[i], bf[j],
                                                            acc[i][j], 0, 0, 0);
    __builtin_amdgcn_s_setprio(0);
    if (pre) { VM_WAIT4; }  // publish A_k0,B_k0 of tile t+1
    __builtin_amdgcn_s_barrier();
  }

  // ------------------------------- epilogue ---------------------------------
  float bv[4];
#pragma unroll
  for (int j = 0; j < 4; ++j)
    bv[j] = bias[(size_t)e * Nd + n0 + wc * 64 + j * 16 + l16];

  if (MODE == 0) {
#pragma unroll
    for (int i = 0; i < 8; ++i) {
      int rowb = r0 + wr * 128 + i * 16 + q * 4;
#pragma unroll
      for (int j = 0; j < 4; ++j) {
        int col = n0 + wc * 64 + j * 16 + l16;
#pragma unroll
        for (int r = 0; r < 4; ++r) {
          float v = acc[i][j][r] + bv[j];
          v = v > 0.0f ? v : 0.0f;
          Hout[(size_t)(e * capR + rowb + r) * Nd + col] = f2bf(v);
        }
      }
    }
  } else {
#pragma unroll
    for (int i = 0; i < 8; ++i) {
      int rowb = r0 + wr * 128 + i * 16 + q * 4;
      int tok[4]; float wv[4];
#pragma unroll
      for (int r = 0; r < 4; ++r) {
        tok[r] = list[e * capR + rowb + r];
        wv[r] = wlist[e * capR + rowb + r];
      }
#pragma unroll
      for (int j = 0; j < 4; ++j) {
        int col = n0 + wc * 64 + j * 16 + l16;
#pragma unroll
        for (int r = 0; r < 4; ++r) {
          float v = (acc[i][j][r] + bv[j]) * wv[r];
          atomicAdd(&out[(size_t)tok[r] * Nd + col], v);
        }
      }
    }
  }
}

// ------------------------------------ host ----------------------------------
extern "C" void kernel_launch(void* const* d_in, const int* in_sizes, int n_in,
                              void* d_out, int out_size, void* d_ws,
                              size_t ws_size, hipStream_t stream) {
  const float* feat  = (const float*)d_in[0];
  const float* Wg    = (const float*)d_in[1];
  const float* bg    = (const float*)d_in[2];
  const float* W1    = (const float*)d_in[3];
  const float* b1    = (const float*)d_in[4];
  const float* W2    = (const float*)d_in[5];
  const float* b2    = (const float*)d_in[6];
  const float* ebias = (const float*)d_in[7];

  const int E = 16;
  const int B = 16384, F = 1024, Hd = 4096, O = 1024;
  const int cap = 2560;            // ceil(1.25*B*2/E)
  const int capR = 2560;           // multiple of 256
  const int nchunk = B / 256;      // 64
  const int RT = capR / 256;       // 10

  char* p = (char*)d_ws;
  auto carve = [&](size_t bytes) {
    char* r = p;
    p += (bytes + 255) & ~(size_t)255;
    return r;
  };
  unsigned short* featbf = (unsigned short*)carve((size_t)B * F * 2);
  unsigned short* W1T = (unsigned short*)carve((size_t)E * Hd * F * 2);
  unsigned short* W2T = (unsigned short*)carve((size_t)E * O * Hd * 2);
  unsigned short* Hbuf = (unsigned short*)carve((size_t)E * capR * Hd * 2);
  int* topki = (int*)carve((size_t)B * 2 * 4);
  float* topkw = (float*)carve((size_t)B * 2 * 4);
  int* hist = (int*)carve((size_t)nchunk * 16 * 4);
  int* choff = (int*)carve((size_t)nchunk * 16 * 4);
  int* cntcl = (int*)carve(16 * 4);
  int* list = (int*)carve((size_t)E * capR * 4);
  float* wlist = (float*)carve((size_t)E * capR * 4);

  hipMemsetAsync(d_out, 0, (size_t)B * O * sizeof(float), stream);
  hipMemsetAsync(hist, 0, (size_t)nchunk * 16 * 4, stream);

  k_cvt_bf16<<<(B * F / 4 + 255) / 256, 256, 0, stream>>>(feat, featbf,
                                                          (long)B * F / 4);
  dim3 tb(32, 8);
  k_txp_bf16<<<dim3(Hd / 32, F / 32, E), tb, 0, stream>>>(W1, W1T, F, Hd);
  k_txp_bf16<<<dim3(O / 32, Hd / 32, E), tb, 0, stream>>>(W2, W2T, Hd, O);
  k_gating<<<256, 256, 0, stream>>>(feat, Wg, bg, ebias, topki, topkw, hist, B, F);
  k_scan<<<1, 64, 0, stream>>>(hist, choff, cntcl, nchunk, cap);
  k_build<<<nchunk, 64, 0, stream>>>(topki, topkw, choff, list, wlist, cap, capR);
  k_padfill<<<E, 256, 0, stream>>>(cntcl, list, wlist, capR);

  k_gemm<0><<<E * RT * (Hd / 256), 512, 0, stream>>>(
      featbf, W1T, b1, list, wlist, cntcl, Hbuf, nullptr, F, Hd, RT, Hd / 256,
      capR);
  k_gemm<1><<<E * RT * (O / 256), 512, 0, stream>>>(
      Hbuf, W2T, b2, list, wlist, cntcl, nullptr, (float*)d_out, Hd, O, RT,
      O / 256, capR);
}